// Round 15
// baseline (42.480 us; speedup 1.0000x reference)
//
#include <hip/hip_runtime.h>
#include <math.h>

#define NB 64
#define V_FULL 6890
#define V_HAND 250
#define V_LOOP 20
#define N_FACES 500
#define FPAD 512      // faces padded with degenerate (v0,v0,v0) -> omega = 0
#define NPTS 251      // V_HAND + 1 (appended loop-mean vertex)
#define NPTS_PAD 256  // pad rows (duplicates of vertex 0)
#define DSLOT 9       // dist-table row = 9 h4 slots (72B): bank-spread pad
#define KSPLIT 32     // lanes per point-quad (face-loop split)
#define PCHUNK 32     // points per block (4 consecutive per thread)
#define NCHUNK 8      // 256 / PCHUNK
#define NITER 16      // FPAD / KSPLIT

struct F3 { float x, y, z; };
typedef float v2f __attribute__((ext_vector_type(2)));
typedef _Float16 h4 __attribute__((ext_vector_type(4)));

// Pair atan2: octant fold to z in [0,1], degree-11 minimax poly,
// err ~1.4e-5 rad. atan2(0, +den) -> 0.
__device__ __forceinline__ v2f atan2_pair(v2f y, v2f x) {
    const float PIO2 = 1.57079632679490f;
    const float PI   = 3.14159265358979f;
    float ax0 = __builtin_fabsf(x.x), ay0 = __builtin_fabsf(y.x);
    float ax1 = __builtin_fabsf(x.y), ay1 = __builtin_fabsf(y.y);
    float mx0 = fmaxf(fmaxf(ax0, ay0), 1e-38f);   // v_max3 candidate
    float mx1 = fmaxf(fmaxf(ax1, ay1), 1e-38f);
    float mn0 = fminf(ax0, ay0);
    float mn1 = fminf(ax1, ay1);
    v2f z;
    z.x = mn0 * __builtin_amdgcn_rcpf(mx0);
    z.y = mn1 * __builtin_amdgcn_rcpf(mx1);
    v2f zz = z * z;
    v2f p  = zz * (-0.01172120f) + 0.05265332f;
    p = zz * p + (-0.11643287f);
    p = zz * p + 0.19354346f;
    p = zz * p + (-0.33262347f);
    p = zz * p + 0.99997726f;
    v2f r = z * p;
    v2f rq = PIO2 - r;
    float r0 = (ay0 > ax0) ? rq.x : r.x;
    float r1 = (ay1 > ax1) ? rq.y : r.y;
    v2f rr; rr.x = r0; rr.y = r1;
    v2f rp = PI - rr;
    r0 = (x.x < 0.0f) ? rp.x : r0;
    r1 = (x.y < 0.0f) ? rp.y : r1;
    v2f out;
    out.x = copysignf(r0, y.x);
    out.y = copysignf(r1, y.y);
    return out;
}

// Grid (NB, 2, NCHUNK) = 1024 blocks -> 4 resident blocks/CU.
// Block 256 = 8 quads x 32 lanes. Quad q owns points 4q..4q+3; lane k
// handles faces k, k+32, ... Inner loop: det = 2D + p.(-2N); dots via law
// of cosines from f16 dist table + per-face edge lengths; no sqrt.
// Loads are software-pipelined one iteration ahead (rotate-by-one) so the
// 2-level LDS chain (face consts -> indices -> dist rows) overlaps math.
__global__ __launch_bounds__(256) void hand_pen_kernel(
    const float* __restrict__ verts,     // [NB][V_FULL][3]
    const int* __restrict__ inds_l,
    const int* __restrict__ inds_r,
    const int* __restrict__ loop_l,
    const int* __restrict__ loop_r,
    const int* __restrict__ faces_l,     // [N_FACES][3]
    const int* __restrict__ faces_r,
    float* __restrict__ partial)         // [NB][2][NCHUNK]
{
    const int b   = blockIdx.x;
    const int dir = blockIdx.y;
    const int z   = blockIdx.z;
    const int tid = threadIdx.x;
    const int q   = tid >> 5;           // point-quad 0..7
    const int k   = tid & 31;           // face-split lane 0..31
    const int q4  = q * 4;

    __shared__ float4 sov[NPTS_PAD];           // other-hand verts (4 KB)
    __shared__ h4     sdist[NPTS_PAD][DSLOT];  // f16 |p-v| table (18 KB)
    __shared__ v2f    snd_xy[FPAD];            // (-2Nx, -2Ny)   (4 KB)
    __shared__ v2f    snd_zw[FPAD];            // (-2Nz,  2D)    (4 KB)
    __shared__ v2f    se_ab[FPAD];             // (e01, e12)     (4 KB)
    __shared__ v2f    se_cw[FPAD];             // (e20, idxbits) (4 KB)
    __shared__ F3     spts[PCHUNK];
    __shared__ float  wave_part[4];

    const float* vb = verts + (size_t)b * V_FULL * 3;
    const int* pind  = (dir == 0) ? inds_l  : inds_r;
    const int* oind  = (dir == 0) ? inds_r  : inds_l;
    const int* ploop = (dir == 0) ? loop_l  : loop_r;
    const int* oloop = (dir == 0) ? loop_r  : loop_l;
    const int* fcs   = (dir == 0) ? faces_r : faces_l;

    // ---- Phase 1: gather other-hand verts (+pad) and this block's 32 points
    {
        int i = tid;
        int go = (i < V_HAND) ? oind[i] : oind[0];   // pad rows = vertex 0
        float4 v = make_float4(vb[go * 3 + 0], vb[go * 3 + 1], vb[go * 3 + 2], 0.f);
        if (i != V_HAND) sov[i] = v;                 // slot 250 = mean, below
    }
    if (tid < 32) {   // other-hand loop mean (20 live lanes, shuffle reduce)
        float sx = 0.f, sy = 0.f, sz = 0.f;
        if (tid < V_LOOP) {
            int gi = oloop[tid];
            sx = vb[gi * 3 + 0]; sy = vb[gi * 3 + 1]; sz = vb[gi * 3 + 2];
        }
        #pragma unroll
        for (int off = 1; off < 32; off <<= 1) {
            sx += __shfl_xor(sx, off);
            sy += __shfl_xor(sy, off);
            sz += __shfl_xor(sz, off);
        }
        if (tid == 0) {
            const float inv = 1.0f / (float)V_LOOP;
            sov[V_HAND] = make_float4(sx * inv, sy * inv, sz * inv, 0.f);
        }
    }
    if (tid >= 64 && tid < 64 + PCHUNK) {   // this block's query points
        int myp = z * PCHUNK + (tid - 64);
        if (myp < V_HAND) {
            int gp = pind[myp];
            F3 qv; qv.x = vb[gp * 3 + 0]; qv.y = vb[gp * 3 + 1]; qv.z = vb[gp * 3 + 2];
            spts[tid - 64] = qv;
        } else if (myp > V_HAND) {
            F3 qv = {0.f, 0.f, 0.f};
            spts[tid - 64] = qv;
        }
    }
    if (tid >= 96 && tid < 128) {  // this-hand loop mean -> point V_HAND
        int l = tid - 96;
        float sx = 0.f, sy = 0.f, sz = 0.f;
        if (l < V_LOOP) {
            int gi = ploop[l];
            sx = vb[gi * 3 + 0]; sy = vb[gi * 3 + 1]; sz = vb[gi * 3 + 2];
        }
        #pragma unroll
        for (int off = 1; off < 32; off <<= 1) {
            sx += __shfl_xor(sx, off);
            sy += __shfl_xor(sy, off);
            sz += __shfl_xor(sz, off);
        }
        if (tid == 96 && V_HAND >= z * PCHUNK && V_HAND < z * PCHUNK + PCHUNK) {
            const float inv = 1.0f / (float)V_LOOP;
            F3 qv; qv.x = sx * inv; qv.y = sy * inv; qv.z = sz * inv;
            spts[V_HAND - z * PCHUNK] = qv;
        }
    }
    __syncthreads();

    // ---- Phase 2a: f16 distance table. Thread t builds row t (vertex t vs
    // all 32 points), 8 h4 slots (b64 writes, 2-way banks).
    {
        float4 v = sov[tid];
        #pragma unroll
        for (int c = 0; c < 8; ++c) {
            F3 p0v = spts[c * 4 + 0];
            F3 p1v = spts[c * 4 + 1];
            F3 p2v = spts[c * 4 + 2];
            F3 p3v = spts[c * 4 + 3];
            float dx, dy, dz, d0f, d1f, d2f, d3f;
            dx = v.x - p0v.x; dy = v.y - p0v.y; dz = v.z - p0v.z;
            d0f = __builtin_amdgcn_sqrtf(dx * dx + dy * dy + dz * dz);
            dx = v.x - p1v.x; dy = v.y - p1v.y; dz = v.z - p1v.z;
            d1f = __builtin_amdgcn_sqrtf(dx * dx + dy * dy + dz * dz);
            dx = v.x - p2v.x; dy = v.y - p2v.y; dz = v.z - p2v.z;
            d2f = __builtin_amdgcn_sqrtf(dx * dx + dy * dy + dz * dz);
            dx = v.x - p3v.x; dy = v.y - p3v.y; dz = v.z - p3v.z;
            d3f = __builtin_amdgcn_sqrtf(dx * dx + dy * dy + dz * dz);
            h4 hh;
            hh.x = (_Float16)d0f; hh.y = (_Float16)d1f;
            hh.z = (_Float16)d2f; hh.w = (_Float16)d3f;
            sdist[tid][c] = hh;
        }
    }

    // ---- Phase 2b: per-face constants, split into v2f arrays for b64
    // conflict-free reads. Pad faces (v0,v0,v0): N=D=0, e2=0 -> omega 0.
    for (int i = tid; i < FPAD; i += 256) {
        float4 v0, v1, v2;
        int i0 = 0, i1 = 0, i2 = 0;
        if (i < N_FACES) {
            i0 = fcs[3 * i + 0]; i1 = fcs[3 * i + 1]; i2 = fcs[3 * i + 2];
        }
        v0 = sov[i0]; v1 = sov[i1]; v2 = sov[i2];
        // u = v1 x v2 ; N = u + v2 x v0 + v0 x v1 ; D = v0 . u
        float ux = v1.y * v2.z - v1.z * v2.y;
        float uy = v1.z * v2.x - v1.x * v2.z;
        float uz = v1.x * v2.y - v1.y * v2.x;
        float Nx = ux + (v2.y * v0.z - v2.z * v0.y) + (v0.y * v1.z - v0.z * v1.y);
        float Ny = uy + (v2.z * v0.x - v2.x * v0.z) + (v0.z * v1.x - v0.x * v1.z);
        float Nz = uz + (v2.x * v0.y - v2.y * v0.x) + (v0.x * v1.y - v0.y * v1.x);
        float D  = v0.x * ux + v0.y * uy + v0.z * uz;
        v2f t;
        t.x = -2.f * Nx; t.y = -2.f * Ny; snd_xy[i] = t;
        t.x = -2.f * Nz; t.y =  2.f * D;  snd_zw[i] = t;
        float ex, ey, ez, e01, e12, e20;
        ex = v0.x - v1.x; ey = v0.y - v1.y; ez = v0.z - v1.z;
        e01 = ex * ex + ey * ey + ez * ez;
        ex = v1.x - v2.x; ey = v1.y - v2.y; ez = v1.z - v2.z;
        e12 = ex * ex + ey * ey + ez * ez;
        ex = v2.x - v0.x; ey = v2.y - v0.y; ez = v2.z - v0.z;
        e20 = ex * ex + ey * ey + ez * ez;
        unsigned int u = (unsigned)i0 | ((unsigned)i1 << 8) | ((unsigned)i2 << 16);
        t.x = e01; t.y = e12; se_ab[i] = t;
        t.x = e20; t.y = __uint_as_float(u); se_cw[i] = t;
    }
    __syncthreads();

    // This thread's 4 consecutive points as two float2 pairs
    const v2f pxA = { spts[q4 + 0].x, spts[q4 + 1].x };
    const v2f pyA = { spts[q4 + 0].y, spts[q4 + 1].y };
    const v2f pzA = { spts[q4 + 0].z, spts[q4 + 1].z };
    const v2f pxB = { spts[q4 + 2].x, spts[q4 + 3].x };
    const v2f pyB = { spts[q4 + 2].y, spts[q4 + 3].y };
    const v2f pzB = { spts[q4 + 2].z, spts[q4 + 3].z };
    const int pbase = z * PCHUNK + q4;

    // ---- Winding: 16 iters, software-pipelined one iteration ahead.
    v2f wsA = {0.f, 0.f}, wsB = {0.f, 0.f};

    // Prologue: load iteration 0's data
    int f = k;
    v2f ndxy = snd_xy[f];
    v2f ndzw = snd_zw[f];
    v2f eab  = se_ab[f];
    v2f ecw  = se_cw[f];
    unsigned int u0 = __float_as_uint(ecw.y);
    h4 ha = sdist[u0 & 255u][q];
    h4 hb = sdist[(u0 >> 8) & 255u][q];
    h4 hc = sdist[(u0 >> 16) & 255u][q];

    #pragma unroll
    for (int it = 0; it < NITER; ++it) {
        // Stash current iteration's operands
        v2f ndxy_c = ndxy, ndzw_c = ndzw, eab_c = eab;
        float ecwx_c = ecw.x;
        h4 ha_c = ha, hb_c = hb, hc_c = hc;

        // Prefetch next iteration's loads (issue before current math)
        if (it < NITER - 1) {
            f += KSPLIT;
            ndxy = snd_xy[f];
            ndzw = snd_zw[f];
            eab  = se_ab[f];
            ecw  = se_cw[f];
            unsigned int un = __float_as_uint(ecw.y);
            ha = sdist[un & 255u][q];
            hb = sdist[(un >> 8) & 255u][q];
            hc = sdist[(un >> 16) & 255u][q];
        }

        // ---- Current iteration's math (operands already in registers)
        v2f daA = { (float)ha_c.x, (float)ha_c.y }, daB = { (float)ha_c.z, (float)ha_c.w };
        v2f dbA = { (float)hb_c.x, (float)hb_c.y }, dbB = { (float)hb_c.z, (float)hb_c.w };
        v2f dcA = { (float)hc_c.x, (float)hc_c.y }, dcB = { (float)hc_c.z, (float)hc_c.w };

        // det = 2D + p.(-2N)
        v2f detA = pxA * ndxy_c.x + (pyA * ndxy_c.y + (pzA * ndzw_c.x + ndzw_c.y));
        v2f detB = pxB * ndxy_c.x + (pyB * ndxy_c.y + (pzB * ndzw_c.x + ndzw_c.y));

        v2f a2A = daA * daA, b2A = dbA * dbA, c2A = dcA * dcA;
        v2f a2B = daB * daB, b2B = dbB * dbB, c2B = dcB * dcB;
        v2f ab2A = (a2A + b2A) - eab_c.x;
        v2f bc2A = (b2A + c2A) - eab_c.y;
        v2f ca2A = (c2A + a2A) - ecwx_c;
        v2f ab2B = (a2B + b2B) - eab_c.x;
        v2f bc2B = (b2B + c2B) - eab_c.y;
        v2f ca2B = (c2B + a2B) - ecwx_c;
        v2f denA = ((daA + daA) * dbA + ab2A) * dcA + (bc2A * daA + ca2A * dbA);
        v2f denB = ((daB + daB) * dbB + ab2B) * dcB + (bc2B * daB + ca2B * dbB);

        wsA += atan2_pair(detA, denA);
        wsB += atan2_pair(detB, denB);
    }

    // ---- Min-dist: scan the f16 dist table (affine rows, b64, 2-way).
    float d0 = 1e30f, d1 = 1e30f, d2m = 1e30f, d3 = 1e30f;
    for (int j = k; j < NPTS_PAD; j += KSPLIT) {
        h4 dd = sdist[j][q];
        d0  = fminf(d0,  (float)dd.x);
        d1  = fminf(d1,  (float)dd.y);
        d2m = fminf(d2m, (float)dd.z);
        d3  = fminf(d3,  (float)dd.w);
    }

    float ws0 = wsA.x, ws1 = wsA.y, ws2 = wsB.x, ws3 = wsB.y;

    // Reduce across the 32-lane group (xor <= 16 stays in wave half)
    #pragma unroll
    for (int off = 1; off <= 16; off <<= 1) {
        ws0 += __shfl_xor(ws0, off);
        ws1 += __shfl_xor(ws1, off);
        ws2 += __shfl_xor(ws2, off);
        ws3 += __shfl_xor(ws3, off);
        d0  = fminf(d0,  __shfl_xor(d0,  off));
        d1  = fminf(d1,  __shfl_xor(d1,  off));
        d2m = fminf(d2m, __shfl_xor(d2m, off));
        d3  = fminf(d3,  __shfl_xor(d3,  off));
    }

    float contrib = 0.0f;
    if (k == 0) {
        if (pbase + 0 < NPTS && ws0 > (float)M_PI) contrib += d0;
        if (pbase + 1 < NPTS && ws1 > (float)M_PI) contrib += d1;
        if (pbase + 2 < NPTS && ws2 > (float)M_PI) contrib += d2m;
        if (pbase + 3 < NPTS && ws3 > (float)M_PI) contrib += d3;
    }

    // Block reduction: wave64 shuffle then 4 partials in LDS
    for (int off = 32; off > 0; off >>= 1)
        contrib += __shfl_down(contrib, off);
    if ((tid & 63) == 0) wave_part[tid >> 6] = contrib;
    __syncthreads();
    if (tid == 0)
        partial[(b * 2 + dir) * NCHUNK + z] =
            wave_part[0] + wave_part[1] + wave_part[2] + wave_part[3];
}

__global__ void combine_kernel(const float* __restrict__ partial, float* __restrict__ out)
{
    int i = threadIdx.x;
    if (i < NB) {
        float s = 0.0f;
        for (int j = 0; j < 2 * NCHUNK; ++j)
            s += partial[i * 2 * NCHUNK + j];
        out[i] = s;
    }
}

extern "C" void kernel_launch(void* const* d_in, const int* in_sizes, int n_in,
                              void* d_out, int out_size, void* d_ws, size_t ws_size,
                              hipStream_t stream) {
    const float* verts  = (const float*)d_in[0];
    const int* inds_l   = (const int*)d_in[1];
    const int* inds_r   = (const int*)d_in[2];
    const int* loop_l   = (const int*)d_in[3];
    const int* loop_r   = (const int*)d_in[4];
    const int* faces_l  = (const int*)d_in[5];
    const int* faces_r  = (const int*)d_in[6];
    float* out = (float*)d_out;
    float* partial = (float*)d_ws;  // NB*2*NCHUNK floats

    hand_pen_kernel<<<dim3(NB, 2, NCHUNK), 256, 0, stream>>>(
        verts, inds_l, inds_r, loop_l, loop_r, faces_l, faces_r, partial);
    combine_kernel<<<1, 64, 0, stream>>>(partial, out);
}

// Round 16
// 28.068 us; speedup vs baseline: 1.5135x; 1.5135x over previous
//
#include <hip/hip_runtime.h>
#include <math.h>

#define NB 64
#define V_FULL 6890
#define V_HAND 250
#define V_LOOP 20
#define N_FACES 500
#define FPAD 512      // faces padded with degenerate (v0,v0,v0) -> omega = 0
#define NPTS 251      // V_HAND + 1 (appended loop-mean vertex)
#define NPTS_PAD 256  // pad rows (duplicates of vertex 0)
#define DSLOT 9       // dist-table row = 9 h4 slots (72B): bank-spread pad
#define KSPLIT 32     // lanes per point-quad (face-loop split)
#define PCHUNK 32     // points per block (4 consecutive per thread)
#define NCHUNK 8      // 256 / PCHUNK

struct F3 { float x, y, z; };
typedef float v2f __attribute__((ext_vector_type(2)));
typedef _Float16 h4 __attribute__((ext_vector_type(4)));

// Pair atan2: poly + range math on float2 (compiler may emit v_pk_*_f32),
// scalar only where irreducible (max/min with |.| mods, rcp, selects,
// copysign). Octant fold to z in [0,1], deg-11 minimax, err ~1.4e-5 rad.
__device__ __forceinline__ v2f atan2_pair(v2f y, v2f x) {
    const float PIO2 = 1.57079632679490f;
    const float PI   = 3.14159265358979f;
    float ax0 = __builtin_fabsf(x.x), ay0 = __builtin_fabsf(y.x);
    float ax1 = __builtin_fabsf(x.y), ay1 = __builtin_fabsf(y.y);
    float mx0 = fmaxf(ax0, ay0), mn0 = fminf(ax0, ay0);
    float mx1 = fmaxf(ax1, ay1), mn1 = fminf(ax1, ay1);
    v2f z;
    z.x = mn0 * __builtin_amdgcn_rcpf(fmaxf(mx0, 1e-38f));
    z.y = mn1 * __builtin_amdgcn_rcpf(fmaxf(mx1, 1e-38f));
    v2f zz = z * z;
    v2f p  = zz * (-0.01172120f) + 0.05265332f;
    p = zz * p + (-0.11643287f);
    p = zz * p + 0.19354346f;
    p = zz * p + (-0.33262347f);
    p = zz * p + 0.99997726f;
    v2f r = z * p;
    v2f rq = PIO2 - r;
    float r0 = (ay0 > ax0) ? rq.x : r.x;
    float r1 = (ay1 > ax1) ? rq.y : r.y;
    v2f rr; rr.x = r0; rr.y = r1;
    v2f rp = PI - rr;
    r0 = (x.x < 0.0f) ? rp.x : r0;
    r1 = (x.y < 0.0f) ? rp.y : r1;
    v2f out;
    out.x = copysignf(r0, y.x);
    out.y = copysignf(r1, y.y);
    return out;
}

// Grid (NB, 2, NCHUNK) = 1024 blocks -> exactly 4 resident blocks/CU.
// Block 256 = 8 quads x 32 lanes. Quad q owns points 4q..4q+3; lane k
// handles faces k, k+32, ... Inner loop: det = 2D + p.(-2N); dots via law
// of cosines from an f16 dist table + per-face edge lengths; no sqrt.
// All LDS reads in the loop are b64 at 2-way-or-less bank aliasing (free).
__global__ __launch_bounds__(256) void hand_pen_kernel(
    const float* __restrict__ verts,     // [NB][V_FULL][3]
    const int* __restrict__ inds_l,
    const int* __restrict__ inds_r,
    const int* __restrict__ loop_l,
    const int* __restrict__ loop_r,
    const int* __restrict__ faces_l,     // [N_FACES][3]
    const int* __restrict__ faces_r,
    float* __restrict__ partial)         // [NB][2][NCHUNK]
{
    const int b   = blockIdx.x;
    const int dir = blockIdx.y;
    const int z   = blockIdx.z;
    const int tid = threadIdx.x;
    const int q   = tid >> 5;           // point-quad 0..7
    const int k   = tid & 31;           // face-split lane 0..31
    const int q4  = q * 4;

    __shared__ float4 sov[NPTS_PAD];           // other-hand verts (4 KB)
    __shared__ h4     sdist[NPTS_PAD][DSLOT];  // f16 |p-v| table (18 KB)
    __shared__ v2f    snd_xy[FPAD];            // (-2Nx, -2Ny)   (4 KB)
    __shared__ v2f    snd_zw[FPAD];            // (-2Nz,  2D)    (4 KB)
    __shared__ v2f    se_ab[FPAD];             // (e01, e12)     (4 KB)
    __shared__ v2f    se_cw[FPAD];             // (e20, idxbits) (4 KB)
    __shared__ F3     spts[PCHUNK];
    __shared__ float  wave_part[4];

    const float* vb = verts + (size_t)b * V_FULL * 3;
    const int* pind  = (dir == 0) ? inds_l  : inds_r;
    const int* oind  = (dir == 0) ? inds_r  : inds_l;
    const int* ploop = (dir == 0) ? loop_l  : loop_r;
    const int* oloop = (dir == 0) ? loop_r  : loop_l;
    const int* fcs   = (dir == 0) ? faces_r : faces_l;

    // ---- Phase 1: gather other-hand verts (+pad) and this block's 32 points
    {
        int i = tid;
        int go = (i < V_HAND) ? oind[i] : oind[0];   // pad rows = vertex 0
        float4 v = make_float4(vb[go * 3 + 0], vb[go * 3 + 1], vb[go * 3 + 2], 0.f);
        if (i != V_HAND) sov[i] = v;                 // slot 250 = mean, below
    }
    if (tid < 32) {   // other-hand loop mean (20 live lanes, shuffle reduce)
        float sx = 0.f, sy = 0.f, sz = 0.f;
        if (tid < V_LOOP) {
            int gi = oloop[tid];
            sx = vb[gi * 3 + 0]; sy = vb[gi * 3 + 1]; sz = vb[gi * 3 + 2];
        }
        #pragma unroll
        for (int off = 1; off < 32; off <<= 1) {
            sx += __shfl_xor(sx, off);
            sy += __shfl_xor(sy, off);
            sz += __shfl_xor(sz, off);
        }
        if (tid == 0) {
            const float inv = 1.0f / (float)V_LOOP;
            sov[V_HAND] = make_float4(sx * inv, sy * inv, sz * inv, 0.f);
        }
    }
    if (tid >= 64 && tid < 64 + PCHUNK) {   // this block's query points
        int myp = z * PCHUNK + (tid - 64);
        if (myp < V_HAND) {
            int gp = pind[myp];
            F3 qv; qv.x = vb[gp * 3 + 0]; qv.y = vb[gp * 3 + 1]; qv.z = vb[gp * 3 + 2];
            spts[tid - 64] = qv;
        } else if (myp > V_HAND) {
            F3 qv = {0.f, 0.f, 0.f};
            spts[tid - 64] = qv;
        }
    }
    if (tid >= 96 && tid < 128) {  // this-hand loop mean -> point V_HAND
        int l = tid - 96;
        float sx = 0.f, sy = 0.f, sz = 0.f;
        if (l < V_LOOP) {
            int gi = ploop[l];
            sx = vb[gi * 3 + 0]; sy = vb[gi * 3 + 1]; sz = vb[gi * 3 + 2];
        }
        #pragma unroll
        for (int off = 1; off < 32; off <<= 1) {
            sx += __shfl_xor(sx, off);
            sy += __shfl_xor(sy, off);
            sz += __shfl_xor(sz, off);
        }
        if (tid == 96 && V_HAND >= z * PCHUNK && V_HAND < z * PCHUNK + PCHUNK) {
            const float inv = 1.0f / (float)V_LOOP;
            F3 qv; qv.x = sx * inv; qv.y = sy * inv; qv.z = sz * inv;
            spts[V_HAND - z * PCHUNK] = qv;
        }
    }
    __syncthreads();

    // ---- Phase 2a: f16 distance table. Thread t builds row t (vertex t vs
    // all 32 points), 8 h4 slots (b64 writes, 2-way banks).
    {
        float4 v = sov[tid];
        #pragma unroll
        for (int c = 0; c < 8; ++c) {
            F3 p0v = spts[c * 4 + 0];
            F3 p1v = spts[c * 4 + 1];
            F3 p2v = spts[c * 4 + 2];
            F3 p3v = spts[c * 4 + 3];
            float dx, dy, dz, d0f, d1f, d2f, d3f;
            dx = v.x - p0v.x; dy = v.y - p0v.y; dz = v.z - p0v.z;
            d0f = __builtin_amdgcn_sqrtf(dx * dx + dy * dy + dz * dz);
            dx = v.x - p1v.x; dy = v.y - p1v.y; dz = v.z - p1v.z;
            d1f = __builtin_amdgcn_sqrtf(dx * dx + dy * dy + dz * dz);
            dx = v.x - p2v.x; dy = v.y - p2v.y; dz = v.z - p2v.z;
            d2f = __builtin_amdgcn_sqrtf(dx * dx + dy * dy + dz * dz);
            dx = v.x - p3v.x; dy = v.y - p3v.y; dz = v.z - p3v.z;
            d3f = __builtin_amdgcn_sqrtf(dx * dx + dy * dy + dz * dz);
            h4 hh;
            hh.x = (_Float16)d0f; hh.y = (_Float16)d1f;
            hh.z = (_Float16)d2f; hh.w = (_Float16)d3f;
            sdist[tid][c] = hh;
        }
    }

    // ---- Phase 2b: per-face constants, split into v2f arrays for b64
    // conflict-free reads. Pad faces (v0,v0,v0): N=D=0, e2=0 -> omega 0.
    for (int i = tid; i < FPAD; i += 256) {
        float4 v0, v1, v2;
        int i0 = 0, i1 = 0, i2 = 0;
        if (i < N_FACES) {
            i0 = fcs[3 * i + 0]; i1 = fcs[3 * i + 1]; i2 = fcs[3 * i + 2];
        }
        v0 = sov[i0]; v1 = sov[i1]; v2 = sov[i2];
        // u = v1 x v2 ; N = u + v2 x v0 + v0 x v1 ; D = v0 . u
        float ux = v1.y * v2.z - v1.z * v2.y;
        float uy = v1.z * v2.x - v1.x * v2.z;
        float uz = v1.x * v2.y - v1.y * v2.x;
        float Nx = ux + (v2.y * v0.z - v2.z * v0.y) + (v0.y * v1.z - v0.z * v1.y);
        float Ny = uy + (v2.z * v0.x - v2.x * v0.z) + (v0.z * v1.x - v0.x * v1.z);
        float Nz = uz + (v2.x * v0.y - v2.y * v0.x) + (v0.x * v1.y - v0.y * v1.x);
        float D  = v0.x * ux + v0.y * uy + v0.z * uz;
        v2f t;
        t.x = -2.f * Nx; t.y = -2.f * Ny; snd_xy[i] = t;
        t.x = -2.f * Nz; t.y =  2.f * D;  snd_zw[i] = t;
        float ex, ey, ez, e01, e12, e20;
        ex = v0.x - v1.x; ey = v0.y - v1.y; ez = v0.z - v1.z;
        e01 = ex * ex + ey * ey + ez * ez;
        ex = v1.x - v2.x; ey = v1.y - v2.y; ez = v1.z - v2.z;
        e12 = ex * ex + ey * ey + ez * ez;
        ex = v2.x - v0.x; ey = v2.y - v0.y; ez = v2.z - v0.z;
        e20 = ex * ex + ey * ey + ez * ez;
        unsigned int u = (unsigned)i0 | ((unsigned)i1 << 8) | ((unsigned)i2 << 16);
        t.x = e01; t.y = e12; se_ab[i] = t;
        t.x = e20; t.y = __uint_as_float(u); se_cw[i] = t;
    }
    __syncthreads();

    // This thread's 4 consecutive points as two float2 pairs (packed math)
    const v2f pxA = { spts[q4 + 0].x, spts[q4 + 1].x };
    const v2f pyA = { spts[q4 + 0].y, spts[q4 + 1].y };
    const v2f pzA = { spts[q4 + 0].z, spts[q4 + 1].z };
    const v2f pxB = { spts[q4 + 2].x, spts[q4 + 3].x };
    const v2f pyB = { spts[q4 + 2].y, spts[q4 + 3].y };
    const v2f pzB = { spts[q4 + 2].z, spts[q4 + 3].z };
    const int pbase = z * PCHUNK + q4;

    // ---- Winding: 16 uniform iters; per face 7 conflict-free b64 reads;
    // pre-atan2 math on float2.
    v2f wsA = {0.f, 0.f}, wsB = {0.f, 0.f};
    #pragma unroll 2
    for (int f = k; f < FPAD; f += KSPLIT) {
        v2f ndxy = snd_xy[f];
        v2f ndzw = snd_zw[f];
        v2f eab  = se_ab[f];
        v2f ecw  = se_cw[f];
        unsigned int u = __float_as_uint(ecw.y);
        h4 ha = sdist[u & 255u][q];
        h4 hb = sdist[(u >> 8) & 255u][q];
        h4 hc = sdist[(u >> 16) & 255u][q];

        v2f daA = { (float)ha.x, (float)ha.y }, daB = { (float)ha.z, (float)ha.w };
        v2f dbA = { (float)hb.x, (float)hb.y }, dbB = { (float)hb.z, (float)hb.w };
        v2f dcA = { (float)hc.x, (float)hc.y }, dcB = { (float)hc.z, (float)hc.w };

        // det = 2D + p.(-2N): 3 pk fma
        v2f detA = pxA * ndxy.x + (pyA * ndxy.y + (pzA * ndzw.x + ndzw.y));
        v2f detB = pxB * ndxy.x + (pyB * ndxy.y + (pzB * ndzw.x + ndzw.y));

        v2f a2A = daA * daA, b2A = dbA * dbA, c2A = dcA * dcA;
        v2f a2B = daB * daB, b2B = dbB * dbB, c2B = dcB * dcB;
        v2f ab2A = (a2A + b2A) - eab.x;
        v2f bc2A = (b2A + c2A) - eab.y;
        v2f ca2A = (c2A + a2A) - ecw.x;
        v2f ab2B = (a2B + b2B) - eab.x;
        v2f bc2B = (b2B + c2B) - eab.y;
        v2f ca2B = (c2B + a2B) - ecw.x;
        v2f denA = ((daA + daA) * dbA + ab2A) * dcA + (bc2A * daA + ca2A * dbA);
        v2f denB = ((daB + daB) * dbB + ab2B) * dcB + (bc2B * daB + ca2B * dbB);

        wsA += atan2_pair(detA, denA);
        wsB += atan2_pair(detB, denB);
    }

    // ---- Min-dist: scan the f16 dist table (affine rows, b64, 2-way).
    float d0 = 1e30f, d1 = 1e30f, d2m = 1e30f, d3 = 1e30f;
    for (int j = k; j < NPTS_PAD; j += KSPLIT) {
        h4 dd = sdist[j][q];
        d0  = fminf(d0,  (float)dd.x);
        d1  = fminf(d1,  (float)dd.y);
        d2m = fminf(d2m, (float)dd.z);
        d3  = fminf(d3,  (float)dd.w);
    }

    float ws0 = wsA.x, ws1 = wsA.y, ws2 = wsB.x, ws3 = wsB.y;

    // Reduce across the 32-lane group (xor <= 16 stays in wave half)
    #pragma unroll
    for (int off = 1; off <= 16; off <<= 1) {
        ws0 += __shfl_xor(ws0, off);
        ws1 += __shfl_xor(ws1, off);
        ws2 += __shfl_xor(ws2, off);
        ws3 += __shfl_xor(ws3, off);
        d0  = fminf(d0,  __shfl_xor(d0,  off));
        d1  = fminf(d1,  __shfl_xor(d1,  off));
        d2m = fminf(d2m, __shfl_xor(d2m, off));
        d3  = fminf(d3,  __shfl_xor(d3,  off));
    }

    float contrib = 0.0f;
    if (k == 0) {
        if (pbase + 0 < NPTS && ws0 > (float)M_PI) contrib += d0;
        if (pbase + 1 < NPTS && ws1 > (float)M_PI) contrib += d1;
        if (pbase + 2 < NPTS && ws2 > (float)M_PI) contrib += d2m;
        if (pbase + 3 < NPTS && ws3 > (float)M_PI) contrib += d3;
    }

    // Block reduction: wave64 shuffle then 4 partials in LDS
    for (int off = 32; off > 0; off >>= 1)
        contrib += __shfl_down(contrib, off);
    if ((tid & 63) == 0) wave_part[tid >> 6] = contrib;
    __syncthreads();
    if (tid == 0)
        partial[(b * 2 + dir) * NCHUNK + z] =
            wave_part[0] + wave_part[1] + wave_part[2] + wave_part[3];
}

__global__ void combine_kernel(const float* __restrict__ partial, float* __restrict__ out)
{
    int i = threadIdx.x;
    if (i < NB) {
        float s = 0.0f;
        for (int j = 0; j < 2 * NCHUNK; ++j)
            s += partial[i * 2 * NCHUNK + j];
        out[i] = s;
    }
}

extern "C" void kernel_launch(void* const* d_in, const int* in_sizes, int n_in,
                              void* d_out, int out_size, void* d_ws, size_t ws_size,
                              hipStream_t stream) {
    const float* verts  = (const float*)d_in[0];
    const int* inds_l   = (const int*)d_in[1];
    const int* inds_r   = (const int*)d_in[2];
    const int* loop_l   = (const int*)d_in[3];
    const int* loop_r   = (const int*)d_in[4];
    const int* faces_l  = (const int*)d_in[5];
    const int* faces_r  = (const int*)d_in[6];
    float* out = (float*)d_out;
    float* partial = (float*)d_ws;  // NB*2*NCHUNK floats

    hand_pen_kernel<<<dim3(NB, 2, NCHUNK), 256, 0, stream>>>(
        verts, inds_l, inds_r, loop_l, loop_r, faces_l, faces_r, partial);
    combine_kernel<<<1, 64, 0, stream>>>(partial, out);
}